// Round 3
// baseline (694.543 us; speedup 1.0000x reference)
//
#include <hip/hip_runtime.h>

#define T_SEQ 2048
#define HID   4096
#define NQH   32
#define NKVH  8
#define HD    128
#define QKV_N 6144  // (32 + 2*8) * 128

typedef __attribute__((ext_vector_type(8))) __bf16 bf16x8;
typedef __attribute__((ext_vector_type(4))) float floatx4;

static __device__ __forceinline__ unsigned short f2bf(float f) {
  union { float f; unsigned u; } v; v.f = f;
  unsigned r = v.u + 0x7fffu + ((v.u >> 16) & 1u);  // RNE
  return (unsigned short)(r >> 16);
}
static __device__ __forceinline__ float bf2f(unsigned short u) {
  union { unsigned u; float f; } v; v.u = ((unsigned)u) << 16;
  return v.f;
}

// async global->LDS, 16B per lane; LDS dest = wave-uniform base + lane*16
static __device__ __forceinline__ void gld_lds16(const unsigned short* g, unsigned short* l) {
  __builtin_amdgcn_global_load_lds(
      (const __attribute__((address_space(1))) unsigned int*)g,
      (__attribute__((address_space(3))) unsigned int*)l, 16, 0, 0);
}

// ---------------- elementwise f32 -> bf16 cast ------------------------------
__global__ __launch_bounds__(256) void cast_f32_bf16(
    const float* __restrict__ in, unsigned short* __restrict__ out) {
  int i = (blockIdx.x * 256 + threadIdx.x) * 4;
  float4 v = *(const float4*)(in + i);
  ushort4 o;
  o.x = f2bf(v.x); o.y = f2bf(v.y); o.z = f2bf(v.z); o.w = f2bf(v.w);
  *(ushort4*)(out + i) = o;
}

// ---------------- f32 [R][C] -> bf16 [C][R] tiled transpose+cast ------------
__global__ __launch_bounds__(256) void transpose_f32_bf16(
    const float* __restrict__ in, unsigned short* __restrict__ out,
    int R, int C) {
  __shared__ unsigned short tile[64][65];
  const int c0 = blockIdx.x * 64, r0 = blockIdx.y * 64;
  const int tr = threadIdx.x >> 4;
  const int tc = (threadIdx.x & 15) * 4;
#pragma unroll
  for (int p = 0; p < 4; p++) {
    int r = tr + p * 16;
    float4 v = *(const float4*)(in + (size_t)(r0 + r) * C + c0 + tc);
    tile[r][tc] = f2bf(v.x); tile[r][tc + 1] = f2bf(v.y);
    tile[r][tc + 2] = f2bf(v.z); tile[r][tc + 3] = f2bf(v.w);
  }
  __syncthreads();
#pragma unroll
  for (int p = 0; p < 4; p++) {
    int c = tr + p * 16;
    ushort4 o;
    o.x = tile[tc][c]; o.y = tile[tc + 1][c]; o.z = tile[tc + 2][c]; o.w = tile[tc + 3][c];
    *(ushort4*)(out + (size_t)(c0 + c) * R + r0 + tc) = o;
  }
}

// ------------- C[M,N] = A[M,K] * Bt[N,K]^T, m97 structure -------------------
__global__ __launch_bounds__(256) void gemm_bt(
    const unsigned short* __restrict__ A, const unsigned short* __restrict__ Bt,
    float* __restrict__ Cf, unsigned short* __restrict__ Cb,
    int M, int N, int K) {
  __shared__ unsigned short As[128][32];
  __shared__ unsigned short Bs[128][32];
  const int tid = threadIdx.x, lane = tid & 63, wv = tid >> 6;
  const int m0 = blockIdx.y * 128, n0 = blockIdx.x * 128;
  const int wm = (wv >> 1) * 64, wn = (wv & 1) * 64;
  const int quad = lane >> 4, mc = lane & 15;
  const int srow = wv * 32 + (lane >> 2);
  const int scol = (lane & 3) * 8;
  const unsigned short* gA = A + (size_t)(m0 + srow) * K + scol;
  const unsigned short* gB = Bt + (size_t)(n0 + srow) * K + scol;
  unsigned short* lA0 = &As[wv * 32][0];
  unsigned short* lA1 = &As[wv * 32 + 16][0];
  unsigned short* lB0 = &Bs[wv * 32][0];
  unsigned short* lB1 = &Bs[wv * 32 + 16][0];
  floatx4 acc[4][4] = {};
  for (int k0 = 0; k0 < K; k0 += 32) {
    gld_lds16(gA + k0, lA0);
    gld_lds16(gA + k0 + (size_t)16 * K, lA1);
    gld_lds16(gB + k0, lB0);
    gld_lds16(gB + k0 + (size_t)16 * K, lB1);
    __syncthreads();
    bf16x8 af[4], bfr[4];
#pragma unroll
    for (int i = 0; i < 4; i++) af[i] = *(const bf16x8*)(&As[wm + i * 16 + mc][quad * 8]);
#pragma unroll
    for (int j = 0; j < 4; j++) bfr[j] = *(const bf16x8*)(&Bs[wn + j * 16 + mc][quad * 8]);
#pragma unroll
    for (int i = 0; i < 4; i++)
#pragma unroll
      for (int j = 0; j < 4; j++)
        acc[i][j] = __builtin_amdgcn_mfma_f32_16x16x32_bf16(af[i], bfr[j], acc[i][j], 0, 0, 0);
    __syncthreads();
  }
#pragma unroll
  for (int i = 0; i < 4; i++)
#pragma unroll
    for (int j = 0; j < 4; j++)
#pragma unroll
      for (int r = 0; r < 4; r++) {
        int row = m0 + wm + i * 16 + quad * 4 + r;
        int col = n0 + wn + j * 16 + mc;
        if (Cf) Cf[(size_t)row * N + col] = acc[i][j][r];
        else    Cb[(size_t)row * N + col] = f2bf(acc[i][j][r]);
      }
}

// ---------- fused per-head RMSNorm + RoPE; V copy + transpose to [kv][d][t] --
__global__ __launch_bounds__(64) void normrope_kernel(
    const unsigned short* __restrict__ qkv,
    const float* __restrict__ qw, const float* __restrict__ kw,
    unsigned short* __restrict__ qout, unsigned short* __restrict__ kout,
    unsigned short* __restrict__ vt) {
  const int t = blockIdx.x, hh = blockIdx.y, ln = threadIdx.x;
  const unsigned short* x = qkv + (size_t)t * QKV_N + hh * HD;
  if (hh >= NQH + NKVH) {
    int kvh = hh - (NQH + NKVH);
    vt[((size_t)kvh * HD + ln) * T_SEQ + t] = x[ln];
    vt[((size_t)kvh * HD + ln + 64) * T_SEQ + t] = x[ln + 64];
    return;
  }
  float x0 = bf2f(x[ln]), x1 = bf2f(x[ln + 64]);
  float ss = x0 * x0 + x1 * x1;
#pragma unroll
  for (int off = 32; off > 0; off >>= 1) ss += __shfl_xor(ss, off, 64);
  float rinv = rsqrtf(ss * (1.0f / 128.0f) + 1e-6f);
  const float* w = (hh < NQH) ? qw : kw;
  float y0 = x0 * rinv * w[ln];
  float y1 = x1 * rinv * w[ln + 64];
  float pos = (float)t;  // positions == arange(T)
  float inv_freq = expf(((float)ln) * (-13.815510557964274f / 64.0f));
  float ang = pos * inv_freq;
  float s, c;
  sincosf(ang, &s, &c);
  float o0 = y0 * c - y1 * s;
  float o1 = y1 * c + y0 * s;
  if (hh < NQH) {
    qout[((size_t)t * NQH + hh) * HD + ln] = f2bf(o0);
    qout[((size_t)t * NQH + hh) * HD + ln + 64] = f2bf(o1);
  } else {
    int kh = hh - NQH;
    kout[((size_t)t * NKVH + kh) * HD + ln] = f2bf(o0);
    kout[((size_t)t * NKVH + kh) * HD + ln + 64] = f2bf(o1);
  }
}

// ---------------- causal GQA attention, no-online-softmax --------------------
// RMSNorm bounds |score| <= sqrt(128) = 11.32, so exp(s) <= 8.2e4 and
// l <= 2048*8.2e4 = 1.7e8: direct exp2 accumulation is f32/bf16-safe.
// grid: (64 q-tiles, 8 kv-heads). qt remap: kvh<4 -> bx, kvh>=4 -> 63-bx.
// With 512 blocks on 256 CUs, block b co-resides with b+256 = (same bx,
// kvh+4) -> complementary work per CU (32-33 tile-units each).
// T14 async-STAGE: next K/V tile global->reg issued before the compute
// barrier, ds_write after the next loop-top barrier.
// REGISTER BUDGET (round-1 lesson): unified VGPR+AGPR usage is ~188 regs
// (72 acc + ~84 arch + 32 staged). __launch_bounds__ min-waves MUST be 2:
// at 3, cap = 168 -> compiler spills the staged tiles to scratch
// (WRITE_SIZE 19->94 MB, dur +20%). Grid is 512 blocks = 2 blocks/CU, so
// min-waves 2 costs nothing.
__global__ __launch_bounds__(256, 2) void attn_kernel(
    const unsigned short* __restrict__ qb, const unsigned short* __restrict__ kb,
    const unsigned short* __restrict__ vt, unsigned short* __restrict__ aout) {
  __shared__ unsigned short smem[27136];      // 54272 B total
  unsigned short* Ks = smem;                  // [64][136]  272B rows
  unsigned short* Vs = smem + 8704;           // [128][72]  144B rows
  unsigned short* Ps = smem + 17920;          // [4][32][72] per-wave P
  const int bx = blockIdx.x;
  const int kvh = blockIdx.y;
  const int qt = (kvh < 4) ? bx : (63 - bx);  // complementary CU pairing
  const int q0 = qt * 32;
  const int tid = threadIdx.x, lane = tid & 63, wv = tid >> 6;
  const int h = kvh * 4 + wv;
  const int quad = lane >> 4, mc = lane & 15;
  const float c2 = 0.1275356394f;  // log2(e)/sqrt(128)
  const __bf16 one = (__bf16)1.0f;
  const bf16x8 ones = {one, one, one, one, one, one, one, one};
  bf16x8 qf[2][4];
#pragma unroll
  for (int mi = 0; mi < 2; mi++)
#pragma unroll
    for (int kc = 0; kc < 4; kc++)
      qf[mi][kc] = *(const bf16x8*)(
          qb + ((size_t)(q0 + mi * 16 + mc) * NQH + h) * HD + kc * 32 + quad * 8);

  // staging addressing (per thread): K row r=p*16+(tid>>4), col d=(tid&15)*8
  //                                  V row d'=p*32+(tid>>3), col s=(tid&7)*8
  const unsigned short* kbase = kb + ((size_t)(tid >> 4) * NKVH + kvh) * HD + (tid & 15) * 8;
  const unsigned short* vbase = vt + ((size_t)kvh * HD + (tid >> 3)) * T_SEQ + (tid & 7) * 8;
  unsigned short* kdst = Ks + (tid >> 4) * 136 + (tid & 15) * 8;
  unsigned short* vdst = Vs + (tid >> 3) * 72 + (tid & 7) * 8;

  floatx4 O[2][8] = {};
  floatx4 lac[2] = {};
  const int ntiles = (qt >> 1) + 1;

  // prologue: tile 0 global->reg
  uint4 kr[4], vr[4];
#pragma unroll
  for (int p = 0; p < 4; p++)
    kr[p] = *(const uint4*)(kbase + (size_t)(p * 16) * (NKVH * HD));
#pragma unroll
  for (int p = 0; p < 4; p++)
    vr[p] = *(const uint4*)(vbase + (size_t)(p * 32) * T_SEQ);

  for (int it = 0; it < ntiles; it++) {
    const int s0 = it * 64;
    __syncthreads();  // prev iter LDS readers done
    // reg -> LDS (waits on the loads issued last iteration; they had the
    // whole previous compute phase to land)
#pragma unroll
    for (int p = 0; p < 4; p++) *(uint4*)(kdst + p * 16 * 136) = kr[p];
#pragma unroll
    for (int p = 0; p < 4; p++) *(uint4*)(vdst + p * 32 * 72) = vr[p];
    // issue next tile's global loads; they fly during this tile's compute
    if (it + 1 < ntiles) {
      const int s0n = s0 + 64;
#pragma unroll
      for (int p = 0; p < 4; p++)
        kr[p] = *(const uint4*)(kbase + (size_t)(s0n + p * 16) * (NKVH * HD));
#pragma unroll
      for (int p = 0; p < 4; p++)
        vr[p] = *(const uint4*)(vbase + (size_t)(p * 32) * T_SEQ + s0n);
    }
    __syncthreads();
    // S = Q K^T -> p = exp2(S*c2) masked -> Ps (A-layout round trip)
#pragma unroll
    for (int jt = 0; jt < 4; jt++) {
      bf16x8 bfr[4];
#pragma unroll
      for (int kc = 0; kc < 4; kc++)
        bfr[kc] = *(const bf16x8*)(Ks + (jt * 16 + mc) * 136 + kc * 32 + quad * 8);
#pragma unroll
      for (int mi = 0; mi < 2; mi++) {
        floatx4 acc = {};
        __builtin_amdgcn_s_setprio(1);
#pragma unroll
        for (int kc = 0; kc < 4; kc++)
          acc = __builtin_amdgcn_mfma_f32_16x16x32_bf16(qf[mi][kc], bfr[kc], acc, 0, 0, 0);
        __builtin_amdgcn_s_setprio(0);
        int qrow = q0 + mi * 16 + quad * 4;
        int scol = s0 + jt * 16 + mc;
#pragma unroll
        for (int r = 0; r < 4; r++) {
          float p = (scol <= qrow + r) ? exp2f(acc[r] * c2) : 0.f;
          Ps[(size_t)(wv * 32 + mi * 16 + quad * 4 + r) * 72 + jt * 16 + mc] = f2bf(p);
        }
      }
    }
    // P A-frags (in-wave DS ordering; Ps region is wave-private)
    bf16x8 pa[2][2];
#pragma unroll
    for (int mi = 0; mi < 2; mi++)
#pragma unroll
      for (int kb2 = 0; kb2 < 2; kb2++)
        pa[mi][kb2] = *(const bf16x8*)(Ps + (size_t)(wv * 32 + mi * 16 + mc) * 72 + kb2 * 32 + quad * 8);
    // row-sum l via MFMA with ones-B (no shuffles)
    __builtin_amdgcn_s_setprio(1);
#pragma unroll
    for (int mi = 0; mi < 2; mi++) {
      lac[mi] = __builtin_amdgcn_mfma_f32_16x16x32_bf16(pa[mi][0], ones, lac[mi], 0, 0, 0);
      lac[mi] = __builtin_amdgcn_mfma_f32_16x16x32_bf16(pa[mi][1], ones, lac[mi], 0, 0, 0);
    }
    __builtin_amdgcn_s_setprio(0);
    // O += P V
#pragma unroll
    for (int jd = 0; jd < 8; jd++) {
      bf16x8 vb0 = *(const bf16x8*)(Vs + (jd * 16 + mc) * 72 + quad * 8);
      bf16x8 vb1 = *(const bf16x8*)(Vs + (jd * 16 + mc) * 72 + 32 + quad * 8);
      __builtin_amdgcn_s_setprio(1);
#pragma unroll
      for (int mi = 0; mi < 2; mi++) {
        O[mi][jd] = __builtin_amdgcn_mfma_f32_16x16x32_bf16(pa[mi][0], vb0, O[mi][jd], 0, 0, 0);
        O[mi][jd] = __builtin_amdgcn_mfma_f32_16x16x32_bf16(pa[mi][1], vb1, O[mi][jd], 0, 0, 0);
      }
      __builtin_amdgcn_s_setprio(0);
    }
  }
  // coalesced epilogue: stage O/l via LDS (reuse whole smem), 16B stores
  __syncthreads();
  float rl[2][4];
#pragma unroll
  for (int mi = 0; mi < 2; mi++)
#pragma unroll
    for (int r = 0; r < 4; r++) rl[mi][r] = 1.0f / lac[mi][r];
#pragma unroll
  for (int mi = 0; mi < 2; mi++)
#pragma unroll
    for (int jd = 0; jd < 8; jd++)
#pragma unroll
      for (int r = 0; r < 4; r++)
        smem[(size_t)(wv * 32 + mi * 16 + quad * 4 + r) * 128 + jd * 16 + mc] =
            f2bf(O[mi][jd][r] * rl[mi][r]);
  __syncthreads();
  const int rr = tid >> 1;            // 0..127: wave wv' = rr>>5, q-row rr&31
  const int cb = (tid & 1) * 64;
  const size_t gbase = (size_t)(q0 + (rr & 31)) * (NQH * HD) + (kvh * 4 + (rr >> 5)) * HD + cb;
#pragma unroll
  for (int i = 0; i < 8; i++) {
    uint4 v = *(const uint4*)(smem + (size_t)rr * 128 + cb + i * 8);
    *(uint4*)(aout + gbase + i * 8) = v;
  }
}

extern "C" void kernel_launch(void* const* d_in, const int* in_sizes, int n_in,
                              void* d_out, int out_size, void* d_ws, size_t ws_size,
                              hipStream_t stream) {
  const float* hidden    = (const float*)d_in[1];  // f32 [2048][4096]
  const float* w_qkv     = (const float*)d_in[2];  // f32 [4096][6144]
  const float* q_norm    = (const float*)d_in[3];  // f32 [128]
  const float* k_norm    = (const float*)d_in[4];  // f32 [128]
  const float* w_o       = (const float*)d_in[5];  // f32 [4096][4096]
  float* out             = (float*)d_out;          // f32 [2048][4096]
  char* ws = (char*)d_ws;
  unsigned short* wqkv_t   = (unsigned short*)(ws);
  unsigned short* q_bf     = (unsigned short*)(ws);               // [2048][32][128]
  unsigned short* k_bf     = (unsigned short*)(ws + 16777216);    // [2048][8][128]
  unsigned short* v_t      = (unsigned short*)(ws + 20971520);    // [8][128][2048]
  unsigned short* attn     = (unsigned short*)(ws + 25165824);    // [2048][4096]
  unsigned short* qkv_bf   = (unsigned short*)(ws + 50331648);    // [2048][6144]
  unsigned short* wo_t     = (unsigned short*)(ws + 50331648);    // [4096][4096]
  unsigned short* hidden_b = (unsigned short*)(ws + 75497472);    // [2048][4096]

  cast_f32_bf16<<<dim3((T_SEQ * HID) / 1024), 256, 0, stream>>>(hidden, hidden_b);
  transpose_f32_bf16<<<dim3(QKV_N / 64, HID / 64), 256, 0, stream>>>(w_qkv, wqkv_t, HID, QKV_N);
  gemm_bt<<<dim3(QKV_N / 128, T_SEQ / 128), 256, 0, stream>>>(
      hidden_b, wqkv_t, nullptr, qkv_bf, T_SEQ, QKV_N, HID);
  normrope_kernel<<<dim3(T_SEQ, NQH + 2 * NKVH), 64, 0, stream>>>(
      qkv_bf, q_norm, k_norm, q_bf, k_bf, v_t);
  transpose_f32_bf16<<<dim3(HID / 64, HID / 64), 256, 0, stream>>>(w_o, wo_t, HID, HID);
  attn_kernel<<<dim3(T_SEQ / 32, NKVH), 256, 0, stream>>>(q_bf, k_bf, v_t, attn);
  gemm_bt<<<dim3(HID / 128, T_SEQ / 128), 256, 0, stream>>>(
      attn, wo_t, out, nullptr, T_SEQ, HID, HID);
}

// Round 4
// 577.918 us; speedup vs baseline: 1.2018x; 1.2018x over previous
//
#include <hip/hip_runtime.h>

#define T_SEQ 2048
#define HID   4096
#define NQH   32
#define NKVH  8
#define HD    128
#define QKV_N 6144  // (32 + 2*8) * 128

typedef __attribute__((ext_vector_type(8))) __bf16 bf16x8;
typedef __attribute__((ext_vector_type(4))) float floatx4;

static __device__ __forceinline__ unsigned short f2bf(float f) {
  union { float f; unsigned u; } v; v.f = f;
  unsigned r = v.u + 0x7fffu + ((v.u >> 16) & 1u);  // RNE
  return (unsigned short)(r >> 16);
}
static __device__ __forceinline__ float bf2f(unsigned short u) {
  union { unsigned u; float f; } v; v.u = ((unsigned)u) << 16;
  return v.f;
}

// async global->LDS, 16B per lane; LDS dest = wave-uniform base + lane*16
static __device__ __forceinline__ void gld_lds16(const unsigned short* g, unsigned short* l) {
  __builtin_amdgcn_global_load_lds(
      (const __attribute__((address_space(1))) unsigned int*)g,
      (__attribute__((address_space(3))) unsigned int*)l, 16, 0, 0);
}

// ---------------- elementwise f32 -> bf16 cast ------------------------------
__global__ __launch_bounds__(256) void cast_f32_bf16(
    const float* __restrict__ in, unsigned short* __restrict__ out) {
  int i = (blockIdx.x * 256 + threadIdx.x) * 4;
  float4 v = *(const float4*)(in + i);
  ushort4 o;
  o.x = f2bf(v.x); o.y = f2bf(v.y); o.z = f2bf(v.z); o.w = f2bf(v.w);
  *(ushort4*)(out + i) = o;
}

// ---------------- f32 [R][C] -> bf16 [C][R] tiled transpose+cast ------------
__global__ __launch_bounds__(256) void transpose_f32_bf16(
    const float* __restrict__ in, unsigned short* __restrict__ out,
    int R, int C) {
  __shared__ unsigned short tile[64][65];
  const int c0 = blockIdx.x * 64, r0 = blockIdx.y * 64;
  const int tr = threadIdx.x >> 4;
  const int tc = (threadIdx.x & 15) * 4;
#pragma unroll
  for (int p = 0; p < 4; p++) {
    int r = tr + p * 16;
    float4 v = *(const float4*)(in + (size_t)(r0 + r) * C + c0 + tc);
    tile[r][tc] = f2bf(v.x); tile[r][tc + 1] = f2bf(v.y);
    tile[r][tc + 2] = f2bf(v.z); tile[r][tc + 3] = f2bf(v.w);
  }
  __syncthreads();
#pragma unroll
  for (int p = 0; p < 4; p++) {
    int c = tr + p * 16;
    ushort4 o;
    o.x = tile[tc][c]; o.y = tile[tc + 1][c]; o.z = tile[tc + 2][c]; o.w = tile[tc + 3][c];
    *(ushort4*)(out + (size_t)(c0 + c) * R + r0 + tc) = o;
  }
}

// ------------- C[M,N] = A[M,K] * Bt[N,K]^T, m97 structure -------------------
__global__ __launch_bounds__(256) void gemm_bt(
    const unsigned short* __restrict__ A, const unsigned short* __restrict__ Bt,
    float* __restrict__ Cf, unsigned short* __restrict__ Cb,
    int M, int N, int K) {
  __shared__ unsigned short As[128][32];
  __shared__ unsigned short Bs[128][32];
  const int tid = threadIdx.x, lane = tid & 63, wv = tid >> 6;
  const int m0 = blockIdx.y * 128, n0 = blockIdx.x * 128;
  const int wm = (wv >> 1) * 64, wn = (wv & 1) * 64;
  const int quad = lane >> 4, mc = lane & 15;
  const int srow = wv * 32 + (lane >> 2);
  const int scol = (lane & 3) * 8;
  const unsigned short* gA = A + (size_t)(m0 + srow) * K + scol;
  const unsigned short* gB = Bt + (size_t)(n0 + srow) * K + scol;
  unsigned short* lA0 = &As[wv * 32][0];
  unsigned short* lA1 = &As[wv * 32 + 16][0];
  unsigned short* lB0 = &Bs[wv * 32][0];
  unsigned short* lB1 = &Bs[wv * 32 + 16][0];
  floatx4 acc[4][4] = {};
  for (int k0 = 0; k0 < K; k0 += 32) {
    gld_lds16(gA + k0, lA0);
    gld_lds16(gA + k0 + (size_t)16 * K, lA1);
    gld_lds16(gB + k0, lB0);
    gld_lds16(gB + k0 + (size_t)16 * K, lB1);
    __syncthreads();
    bf16x8 af[4], bfr[4];
#pragma unroll
    for (int i = 0; i < 4; i++) af[i] = *(const bf16x8*)(&As[wm + i * 16 + mc][quad * 8]);
#pragma unroll
    for (int j = 0; j < 4; j++) bfr[j] = *(const bf16x8*)(&Bs[wn + j * 16 + mc][quad * 8]);
#pragma unroll
    for (int i = 0; i < 4; i++)
#pragma unroll
      for (int j = 0; j < 4; j++)
        acc[i][j] = __builtin_amdgcn_mfma_f32_16x16x32_bf16(af[i], bfr[j], acc[i][j], 0, 0, 0);
    __syncthreads();
  }
#pragma unroll
  for (int i = 0; i < 4; i++)
#pragma unroll
    for (int j = 0; j < 4; j++)
#pragma unroll
      for (int r = 0; r < 4; r++) {
        int row = m0 + wm + i * 16 + quad * 4 + r;
        int col = n0 + wn + j * 16 + mc;
        if (Cf) Cf[(size_t)row * N + col] = acc[i][j][r];
        else    Cb[(size_t)row * N + col] = f2bf(acc[i][j][r]);
      }
}

// ---------- fused per-head RMSNorm + RoPE; V copy + transpose to [kv][d][t] --
__global__ __launch_bounds__(64) void normrope_kernel(
    const unsigned short* __restrict__ qkv,
    const float* __restrict__ qw, const float* __restrict__ kw,
    unsigned short* __restrict__ qout, unsigned short* __restrict__ kout,
    unsigned short* __restrict__ vt) {
  const int t = blockIdx.x, hh = blockIdx.y, ln = threadIdx.x;
  const unsigned short* x = qkv + (size_t)t * QKV_N + hh * HD;
  if (hh >= NQH + NKVH) {
    int kvh = hh - (NQH + NKVH);
    vt[((size_t)kvh * HD + ln) * T_SEQ + t] = x[ln];
    vt[((size_t)kvh * HD + ln + 64) * T_SEQ + t] = x[ln + 64];
    return;
  }
  float x0 = bf2f(x[ln]), x1 = bf2f(x[ln + 64]);
  float ss = x0 * x0 + x1 * x1;
#pragma unroll
  for (int off = 32; off > 0; off >>= 1) ss += __shfl_xor(ss, off, 64);
  float rinv = rsqrtf(ss * (1.0f / 128.0f) + 1e-6f);
  const float* w = (hh < NQH) ? qw : kw;
  float y0 = x0 * rinv * w[ln];
  float y1 = x1 * rinv * w[ln + 64];
  float pos = (float)t;  // positions == arange(T)
  float inv_freq = expf(((float)ln) * (-13.815510557964274f / 64.0f));
  float ang = pos * inv_freq;
  float s, c;
  sincosf(ang, &s, &c);
  float o0 = y0 * c - y1 * s;
  float o1 = y1 * c + y0 * s;
  if (hh < NQH) {
    qout[((size_t)t * NQH + hh) * HD + ln] = f2bf(o0);
    qout[((size_t)t * NQH + hh) * HD + ln + 64] = f2bf(o1);
  } else {
    int kh = hh - NQH;
    kout[((size_t)t * NKVH + kh) * HD + ln] = f2bf(o0);
    kout[((size_t)t * NKVH + kh) * HD + ln + 64] = f2bf(o1);
  }
}

// ---------------- causal GQA attention, no-online-softmax --------------------
// RMSNorm bounds |score| <= sqrt(128) = 11.32, so exp(s) <= 8.2e4 and
// l <= 2048*8.2e4 = 1.7e8: direct exp2 accumulation is f32/bf16-safe.
// T14 async-STAGE, attempt 3 (round 1/3 lesson): uint4 ARRAYS kr[4]/vr[4]
// were demoted to scratch by LLVM regardless of the launch-bounds register
// cap (VGPR_Count pinned at 84, WRITE_SIZE 19->95 MB both at minwaves 3
// and 2) -- rule-#20 failure mode. Fix: eight individually-NAMED uint4
// locals, all accesses compile-time static. Spill discriminator for this
// run: VGPR_Count must rise to ~116+ and WRITE_SIZE fall to ~19 MB.
__global__ __launch_bounds__(256, 2) void attn_kernel(
    const unsigned short* __restrict__ qb, const unsigned short* __restrict__ kb,
    const unsigned short* __restrict__ vt, unsigned short* __restrict__ aout) {
  __shared__ unsigned short smem[27136];      // 54272 B total
  unsigned short* Ks = smem;                  // [64][136]  272B rows
  unsigned short* Vs = smem + 8704;           // [128][72]  144B rows
  unsigned short* Ps = smem + 17920;          // [4][32][72] per-wave P
  const int bx = blockIdx.x;
  const int kvh = blockIdx.y;
  const int qt = (kvh < 4) ? bx : (63 - bx);  // complementary CU pairing
  const int q0 = qt * 32;
  const int tid = threadIdx.x, lane = tid & 63, wv = tid >> 6;
  const int h = kvh * 4 + wv;
  const int quad = lane >> 4, mc = lane & 15;
  const float c2 = 0.1275356394f;  // log2(e)/sqrt(128)
  const __bf16 one = (__bf16)1.0f;
  const bf16x8 ones = {one, one, one, one, one, one, one, one};
  bf16x8 qf[2][4];
#pragma unroll
  for (int mi = 0; mi < 2; mi++)
#pragma unroll
    for (int kc = 0; kc < 4; kc++)
      qf[mi][kc] = *(const bf16x8*)(
          qb + ((size_t)(q0 + mi * 16 + mc) * NQH + h) * HD + kc * 32 + quad * 8);

  // staging addressing (per thread): K row r=p*16+(tid>>4), col d=(tid&15)*8
  //                                  V row d'=p*32+(tid>>3), col s=(tid&7)*8
  const unsigned short* kbase = kb + ((size_t)(tid >> 4) * NKVH + kvh) * HD + (tid & 15) * 8;
  const unsigned short* vbase = vt + ((size_t)kvh * HD + (tid >> 3)) * T_SEQ + (tid & 7) * 8;
  unsigned short* kdst = Ks + (tid >> 4) * 136 + (tid & 15) * 8;
  unsigned short* vdst = Vs + (tid >> 3) * 72 + (tid & 7) * 8;
  const size_t kstep = (size_t)16 * (NKVH * HD);   // 16 K-rows
  const size_t vstep = (size_t)32 * T_SEQ;         // 32 V-d-rows

  floatx4 O[2][8] = {};
  floatx4 lac[2] = {};
  const int ntiles = (qt >> 1) + 1;

  // prologue: tile 0 global->reg (named regs, static uses only)
  uint4 kr0 = *(const uint4*)(kbase);
  uint4 kr1 = *(const uint4*)(kbase + kstep);
  uint4 kr2 = *(const uint4*)(kbase + 2 * kstep);
  uint4 kr3 = *(const uint4*)(kbase + 3 * kstep);
  uint4 vr0 = *(const uint4*)(vbase);
  uint4 vr1 = *(const uint4*)(vbase + vstep);
  uint4 vr2 = *(const uint4*)(vbase + 2 * vstep);
  uint4 vr3 = *(const uint4*)(vbase + 3 * vstep);

  for (int it = 0; it < ntiles; it++) {
    const int s0 = it * 64;
    __syncthreads();  // prev iter LDS readers done
    // reg -> LDS (waits on loads issued one compute-phase ago)
    *(uint4*)(kdst)                = kr0;
    *(uint4*)(kdst + 16 * 136)     = kr1;
    *(uint4*)(kdst + 32 * 136)     = kr2;
    *(uint4*)(kdst + 48 * 136)     = kr3;
    *(uint4*)(vdst)                = vr0;
    *(uint4*)(vdst + 32 * 72)      = vr1;
    *(uint4*)(vdst + 64 * 72)      = vr2;
    *(uint4*)(vdst + 96 * 72)      = vr3;
    // issue next tile's global loads NOW; they fly during this tile's compute
    if (it + 1 < ntiles) {
      const int s0n = s0 + 64;
      const unsigned short* kn = kbase + (size_t)s0n * (NKVH * HD);
      const unsigned short* vn = vbase + s0n;
      kr0 = *(const uint4*)(kn);
      kr1 = *(const uint4*)(kn + kstep);
      kr2 = *(const uint4*)(kn + 2 * kstep);
      kr3 = *(const uint4*)(kn + 3 * kstep);
      vr0 = *(const uint4*)(vn);
      vr1 = *(const uint4*)(vn + vstep);
      vr2 = *(const uint4*)(vn + 2 * vstep);
      vr3 = *(const uint4*)(vn + 3 * vstep);
    }
    __syncthreads();
    // S = Q K^T -> p = exp2(S*c2) masked -> Ps (A-layout round trip)
#pragma unroll
    for (int jt = 0; jt < 4; jt++) {
      bf16x8 bfr[4];
#pragma unroll
      for (int kc = 0; kc < 4; kc++)
        bfr[kc] = *(const bf16x8*)(Ks + (jt * 16 + mc) * 136 + kc * 32 + quad * 8);
#pragma unroll
      for (int mi = 0; mi < 2; mi++) {
        floatx4 acc = {};
        __builtin_amdgcn_s_setprio(1);
#pragma unroll
        for (int kc = 0; kc < 4; kc++)
          acc = __builtin_amdgcn_mfma_f32_16x16x32_bf16(qf[mi][kc], bfr[kc], acc, 0, 0, 0);
        __builtin_amdgcn_s_setprio(0);
        int qrow = q0 + mi * 16 + quad * 4;
        int scol = s0 + jt * 16 + mc;
#pragma unroll
        for (int r = 0; r < 4; r++) {
          float p = (scol <= qrow + r) ? exp2f(acc[r] * c2) : 0.f;
          Ps[(size_t)(wv * 32 + mi * 16 + quad * 4 + r) * 72 + jt * 16 + mc] = f2bf(p);
        }
      }
    }
    // P A-frags (in-wave DS ordering; Ps region is wave-private)
    bf16x8 pa[2][2];
#pragma unroll
    for (int mi = 0; mi < 2; mi++)
#pragma unroll
      for (int kb2 = 0; kb2 < 2; kb2++)
        pa[mi][kb2] = *(const bf16x8*)(Ps + (size_t)(wv * 32 + mi * 16 + mc) * 72 + kb2 * 32 + quad * 8);
    // row-sum l via MFMA with ones-B (no shuffles)
    __builtin_amdgcn_s_setprio(1);
#pragma unroll
    for (int mi = 0; mi < 2; mi++) {
      lac[mi] = __builtin_amdgcn_mfma_f32_16x16x32_bf16(pa[mi][0], ones, lac[mi], 0, 0, 0);
      lac[mi] = __builtin_amdgcn_mfma_f32_16x16x32_bf16(pa[mi][1], ones, lac[mi], 0, 0, 0);
    }
    __builtin_amdgcn_s_setprio(0);
    // O += P V
#pragma unroll
    for (int jd = 0; jd < 8; jd++) {
      bf16x8 vb0 = *(const bf16x8*)(Vs + (jd * 16 + mc) * 72 + quad * 8);
      bf16x8 vb1 = *(const bf16x8*)(Vs + (jd * 16 + mc) * 72 + 32 + quad * 8);
      __builtin_amdgcn_s_setprio(1);
#pragma unroll
      for (int mi = 0; mi < 2; mi++) {
        O[mi][jd] = __builtin_amdgcn_mfma_f32_16x16x32_bf16(pa[mi][0], vb0, O[mi][jd], 0, 0, 0);
        O[mi][jd] = __builtin_amdgcn_mfma_f32_16x16x32_bf16(pa[mi][1], vb1, O[mi][jd], 0, 0, 0);
      }
      __builtin_amdgcn_s_setprio(0);
    }
  }
  // coalesced epilogue: stage O/l via LDS (reuse whole smem), 16B stores
  __syncthreads();
  float rl[2][4];
#pragma unroll
  for (int mi = 0; mi < 2; mi++)
#pragma unroll
    for (int r = 0; r < 4; r++) rl[mi][r] = 1.0f / lac[mi][r];
#pragma unroll
  for (int mi = 0; mi < 2; mi++)
#pragma unroll
    for (int jd = 0; jd < 8; jd++)
#pragma unroll
      for (int r = 0; r < 4; r++)
        smem[(size_t)(wv * 32 + mi * 16 + quad * 4 + r) * 128 + jd * 16 + mc] =
            f2bf(O[mi][jd][r] * rl[mi][r]);
  __syncthreads();
  const int rr = tid >> 1;            // 0..127: wave wv' = rr>>5, q-row rr&31
  const int cb = (tid & 1) * 64;
  const size_t gbase = (size_t)(q0 + (rr & 31)) * (NQH * HD) + (kvh * 4 + (rr >> 5)) * HD + cb;
#pragma unroll
  for (int i = 0; i < 8; i++) {
    uint4 v = *(const uint4*)(smem + (size_t)rr * 128 + cb + i * 8);
    *(uint4*)(aout + gbase + i * 8) = v;
  }
}

extern "C" void kernel_launch(void* const* d_in, const int* in_sizes, int n_in,
                              void* d_out, int out_size, void* d_ws, size_t ws_size,
                              hipStream_t stream) {
  const float* hidden    = (const float*)d_in[1];  // f32 [2048][4096]
  const float* w_qkv     = (const float*)d_in[2];  // f32 [4096][6144]
  const float* q_norm    = (const float*)d_in[3];  // f32 [128]
  const float* k_norm    = (const float*)d_in[4];  // f32 [128]
  const float* w_o       = (const float*)d_in[5];  // f32 [4096][4096]
  float* out             = (float*)d_out;          // f32 [2048][4096]
  char* ws = (char*)d_ws;
  unsigned short* wqkv_t   = (unsigned short*)(ws);
  unsigned short* q_bf     = (unsigned short*)(ws);               // [2048][32][128]
  unsigned short* k_bf     = (unsigned short*)(ws + 16777216);    // [2048][8][128]
  unsigned short* v_t      = (unsigned short*)(ws + 20971520);    // [8][128][2048]
  unsigned short* attn     = (unsigned short*)(ws + 25165824);    // [2048][4096]
  unsigned short* qkv_bf   = (unsigned short*)(ws + 50331648);    // [2048][6144]
  unsigned short* wo_t     = (unsigned short*)(ws + 50331648);    // [4096][4096]
  unsigned short* hidden_b = (unsigned short*)(ws + 75497472);    // [2048][4096]

  cast_f32_bf16<<<dim3((T_SEQ * HID) / 1024), 256, 0, stream>>>(hidden, hidden_b);
  transpose_f32_bf16<<<dim3(QKV_N / 64, HID / 64), 256, 0, stream>>>(w_qkv, wqkv_t, HID, QKV_N);
  gemm_bt<<<dim3(QKV_N / 128, T_SEQ / 128), 256, 0, stream>>>(
      hidden_b, wqkv_t, nullptr, qkv_bf, T_SEQ, QKV_N, HID);
  normrope_kernel<<<dim3(T_SEQ, NQH + 2 * NKVH), 64, 0, stream>>>(
      qkv_bf, q_norm, k_norm, q_bf, k_bf, v_t);
  transpose_f32_bf16<<<dim3(HID / 64, HID / 64), 256, 0, stream>>>(w_o, wo_t, HID, HID);
  attn_kernel<<<dim3(T_SEQ / 32, NKVH), 256, 0, stream>>>(q_bf, k_bf, v_t, attn);
  gemm_bt<<<dim3(HID / 128, T_SEQ / 128), 256, 0, stream>>>(
      attn, wo_t, out, nullptr, T_SEQ, HID, HID);
}

// Round 10
// 520.308 us; speedup vs baseline: 1.3349x; 1.1107x over previous
//
#include <hip/hip_runtime.h>

#define T_SEQ 2048
#define HID   4096
#define NQH   32
#define NKVH  8
#define HD    128
#define QKV_N 6144  // (32 + 2*8) * 128

typedef __attribute__((ext_vector_type(8))) __bf16 bf16x8;
typedef __attribute__((ext_vector_type(4))) float floatx4;

static __device__ __forceinline__ unsigned short f2bf(float f) {
  union { float f; unsigned u; } v; v.f = f;
  unsigned r = v.u + 0x7fffu + ((v.u >> 16) & 1u);  // RNE
  return (unsigned short)(r >> 16);
}
static __device__ __forceinline__ float bf2f(unsigned short u) {
  union { unsigned u; float f; } v; v.u = ((unsigned)u) << 16;
  return v.f;
}

// async global->LDS, 16B per lane; LDS dest = wave-uniform base + lane*16
static __device__ __forceinline__ void gld_lds16(const unsigned short* g, unsigned short* l) {
  __builtin_amdgcn_global_load_lds(
      (const __attribute__((address_space(1))) unsigned int*)g,
      (__attribute__((address_space(3))) unsigned int*)l, 16, 0, 0);
}

// ---------------- elementwise f32 -> bf16 cast ------------------------------
__global__ __launch_bounds__(256) void cast_f32_bf16(
    const float* __restrict__ in, unsigned short* __restrict__ out) {
  int i = (blockIdx.x * 256 + threadIdx.x) * 4;
  float4 v = *(const float4*)(in + i);
  ushort4 o;
  o.x = f2bf(v.x); o.y = f2bf(v.y); o.z = f2bf(v.z); o.w = f2bf(v.w);
  *(ushort4*)(out + i) = o;
}

// ---------------- f32 [R][C] -> bf16 [C][R] tiled transpose+cast ------------
__global__ __launch_bounds__(256) void transpose_f32_bf16(
    const float* __restrict__ in, unsigned short* __restrict__ out,
    int R, int C) {
  __shared__ unsigned short tile[64][65];
  const int c0 = blockIdx.x * 64, r0 = blockIdx.y * 64;
  const int tr = threadIdx.x >> 4;
  const int tc = (threadIdx.x & 15) * 4;
#pragma unroll
  for (int p = 0; p < 4; p++) {
    int r = tr + p * 16;
    float4 v = *(const float4*)(in + (size_t)(r0 + r) * C + c0 + tc);
    tile[r][tc] = f2bf(v.x); tile[r][tc + 1] = f2bf(v.y);
    tile[r][tc + 2] = f2bf(v.z); tile[r][tc + 3] = f2bf(v.w);
  }
  __syncthreads();
#pragma unroll
  for (int p = 0; p < 4; p++) {
    int c = tr + p * 16;
    ushort4 o;
    o.x = tile[tc][c]; o.y = tile[tc + 1][c]; o.z = tile[tc + 2][c]; o.w = tile[tc + 3][c];
    *(ushort4*)(out + (size_t)(c0 + c) * R + r0 + tc) = o;
  }
}

// ---- C[M,N] = A[M,K] * Bt[N,K]^T -- 256-row tile, 8-wave, 4-phase pipeline --
// BM=256, BN in {128,256}, BK=64, 512 threads (8 waves, 2M x 4N grid).
// LDS: double-buffered A[256][64] + B[BN][64] bf16, rows 128B, with T2 slot
// swizzle: phys 16B-slot = logical_slot ^ (row&7). Staging (gld_lds writes
// linearly, rule #21) pre-permutes the per-lane GLOBAL source so LDS content
// lands swizzled; frag reads apply the same XOR (per-lane constant since all
// frag rows have row&7 == mc&7). Balances ds_read_b128 to exactly 8
// accesses/bank (the b128 conflict-free condition) vs 16/bank linear.
// Schedule (T3-lite): stages for K-tile t+1 issue spread across tile t's 4
// MFMA phases; ONE vmcnt(0)+s_barrier per K-tile, waiting loads issued a
// full iteration earlier (drain ~free, unlike m97's same-step drain).
// T5 setprio wraps each MFMA cluster (phased schedule -> it pays, m218b).
template <int BN>
__global__ __launch_bounds__(512, 2) void gemm_bt2(
    const unsigned short* __restrict__ A, const unsigned short* __restrict__ Bt,
    float* __restrict__ Cf, unsigned short* __restrict__ Cb,
    int M, int N, int K) {
  constexpr int NJ = BN / 64;  // col-frags per wave == B stage-issues per tile
  __shared__ unsigned short lds[2 * 16384 + 2 * BN * 64];
  const int tid = threadIdx.x, lane = tid & 63, wv = tid >> 6;
  const int quad = lane >> 4, mc = lane & 15;
  const int wr = wv >> 2, wc = wv & 3;  // wave grid 2(M) x 4(N)
  const int m0 = blockIdx.y * 256, n0 = blockIdx.x * BN;
  const int NK = K >> 6;
  unsigned short* curA = lds;
  unsigned short* nxtA = lds + 16384;
  unsigned short* curB = lds + 32768;
  unsigned short* nxtB = lds + 32768 + BN * 64;
  // stage source addressing: issue i covers phys LDS bytes [i*8192,(i+1)*8192)
  // thread covers phys o = i*8192 + tid*16: row = i*64 + (tid>>3),
  // phys slot = tid&7, logical slot = phys ^ (row&7)  (inverse-swizzled src)
  const int arow = tid >> 3;
  const int sl8 = (((tid & 7) ^ (arow & 7)) << 3);  // logical slot * 8 shorts
  const unsigned short* gA = A + (size_t)(m0 + arow) * K + sl8;
  const unsigned short* gB = Bt + (size_t)(n0 + arow) * K + sl8;
  const int ldst = wv * 512;  // wave-uniform dest offset (shorts) within issue
  const size_t kW = (size_t)64 * K;  // 64 global rows (one issue's row span)
  // swizzled in-row offsets for frag reads (shorts); slot = kk*4 + quad,
  // row&7 == mc&7 for every frag row -> per-lane constant
  const int s0 = ((quad ^ (mc & 7)) << 3);
  const int s1 = (((4 + quad) ^ (mc & 7)) << 3);
  floatx4 acc[8][NJ] = {};
  // prologue: stage tile 0 into cur buffers
#pragma unroll
  for (int i = 0; i < NJ; ++i) gld_lds16(gB + (size_t)i * kW, curB + i * 4096 + ldst);
#pragma unroll
  for (int i = 0; i < 4; ++i)  gld_lds16(gA + (size_t)i * kW, curA + i * 4096 + ldst);

#define GPHASE(I0)                                                                   \
  do {                                                                               \
    const unsigned short* p0_ = curA + (wr * 128 + (I0) * 16 + mc) * 64;             \
    const unsigned short* p1_ = p0_ + 16 * 64;                                       \
    bf16x8 a00 = *(const bf16x8*)(p0_ + s0), a01 = *(const bf16x8*)(p0_ + s1);       \
    bf16x8 a10 = *(const bf16x8*)(p1_ + s0), a11 = *(const bf16x8*)(p1_ + s1);       \
    __builtin_amdgcn_s_setprio(1);                                                   \
    _Pragma("unroll")                                                                \
    for (int j = 0; j < NJ; ++j) {                                                   \
      acc[(I0)][j] = __builtin_amdgcn_mfma_f32_16x16x32_bf16(a00, bfr[j][0], acc[(I0)][j], 0, 0, 0);     \
      acc[(I0)][j] = __builtin_amdgcn_mfma_f32_16x16x32_bf16(a01, bfr[j][1], acc[(I0)][j], 0, 0, 0);     \
      acc[(I0)+1][j] = __builtin_amdgcn_mfma_f32_16x16x32_bf16(a10, bfr[j][0], acc[(I0)+1][j], 0, 0, 0); \
      acc[(I0)+1][j] = __builtin_amdgcn_mfma_f32_16x16x32_bf16(a11, bfr[j][1], acc[(I0)+1][j], 0, 0, 0); \
    }                                                                                \
    __builtin_amdgcn_s_setprio(0);                                                   \
  } while (0)

  for (int kt = 0; kt < NK; ++kt) {
    // tile-kt stages (issued one full iteration ago) land; publish to all
    // waves; also fences prev-iter reads vs the upcoming nxt-buffer writes
    asm volatile("s_waitcnt vmcnt(0)\n\ts_barrier" ::: "memory");
    const bool pre = (kt + 1 < NK);
    const unsigned short* gAn = gA + (size_t)(kt + 1) * 64;
    const unsigned short* gBn = gB + (size_t)(kt + 1) * 64;
    // ---- phase 0: stage B0,B1(t+1); read all B-frags + A rows 0,1
    if (pre) { gld_lds16(gBn, nxtB + ldst); gld_lds16(gBn + kW, nxtB + 4096 + ldst); }
    bf16x8 bfr[NJ][2];
#pragma unroll
    for (int j = 0; j < NJ; ++j) {
      const unsigned short* p = curB + (wc * (16 * NJ) + j * 16 + mc) * 64;
      bfr[j][0] = *(const bf16x8*)(p + s0);
      bfr[j][1] = *(const bf16x8*)(p + s1);
    }
    GPHASE(0);
    // ---- phase 1
    if (pre) {
      if constexpr (NJ == 4) {
        gld_lds16(gBn + 2 * kW, nxtB + 8192 + ldst);
        gld_lds16(gBn + 3 * kW, nxtB + 12288 + ldst);
      } else {
        gld_lds16(gAn, nxtA + ldst);
        gld_lds16(gAn + kW, nxtA + 4096 + ldst);
      }
    }
    GPHASE(2);
    // ---- phase 2
    if (pre) {
      if constexpr (NJ == 4) {
        gld_lds16(gAn, nxtA + ldst);
        gld_lds16(gAn + kW, nxtA + 4096 + ldst);
      } else {
        gld_lds16(gAn + 2 * kW, nxtA + 8192 + ldst);
        gld_lds16(gAn + 3 * kW, nxtA + 12288 + ldst);
      }
    }
    GPHASE(4);
    // ---- phase 3
    if (pre) {
      if constexpr (NJ == 4) {
        gld_lds16(gAn + 2 * kW, nxtA + 8192 + ldst);
        gld_lds16(gAn + 3 * kW, nxtA + 12288 + ldst);
      }
    }
    GPHASE(6);
    // swap double buffers
    { unsigned short* t = curA; curA = nxtA; nxtA = t;
      t = curB; curB = nxtB; nxtB = t; }
  }
#undef GPHASE
  // epilogue
#pragma unroll
  for (int i = 0; i < 8; ++i)
#pragma unroll
    for (int j = 0; j < NJ; ++j)
#pragma unroll
      for (int r = 0; r < 4; ++r) {
        int row = m0 + wr * 128 + i * 16 + quad * 4 + r;
        int col = n0 + wc * (16 * NJ) + j * 16 + mc;
        if (Cf) Cf[(size_t)row * N + col] = acc[i][j][r];
        else    Cb[(size_t)row * N + col] = f2bf(acc[i][j][r]);
      }
}

// ---------- fused per-head RMSNorm + RoPE; V copy + transpose to [kv][d][t] --
__global__ __launch_bounds__(64) void normrope_kernel(
    const unsigned short* __restrict__ qkv,
    const float* __restrict__ qw, const float* __restrict__ kw,
    unsigned short* __restrict__ qout, unsigned short* __restrict__ kout,
    unsigned short* __restrict__ vt) {
  const int t = blockIdx.x, hh = blockIdx.y, ln = threadIdx.x;
  const unsigned short* x = qkv + (size_t)t * QKV_N + hh * HD;
  if (hh >= NQH + NKVH) {
    int kvh = hh - (NQH + NKVH);
    vt[((size_t)kvh * HD + ln) * T_SEQ + t] = x[ln];
    vt[((size_t)kvh * HD + ln + 64) * T_SEQ + t] = x[ln + 64];
    return;
  }
  float x0 = bf2f(x[ln]), x1 = bf2f(x[ln + 64]);
  float ss = x0 * x0 + x1 * x1;
#pragma unroll
  for (int off = 32; off > 0; off >>= 1) ss += __shfl_xor(ss, off, 64);
  float rinv = rsqrtf(ss * (1.0f / 128.0f) + 1e-6f);
  const float* w = (hh < NQH) ? qw : kw;
  float y0 = x0 * rinv * w[ln];
  float y1 = x1 * rinv * w[ln + 64];
  float pos = (float)t;  // positions == arange(T)
  float inv_freq = expf(((float)ln) * (-13.815510557964274f / 64.0f));
  float ang = pos * inv_freq;
  float s, c;
  sincosf(ang, &s, &c);
  float o0 = y0 * c - y1 * s;
  float o1 = y1 * c + y0 * s;
  if (hh < NQH) {
    qout[((size_t)t * NQH + hh) * HD + ln] = f2bf(o0);
    qout[((size_t)t * NQH + hh) * HD + ln + 64] = f2bf(o1);
  } else {
    int kh = hh - NQH;
    kout[((size_t)t * NKVH + kh) * HD + ln] = f2bf(o0);
    kout[((size_t)t * NKVH + kh) * HD + ln + 64] = f2bf(o1);
  }
}

// ---------------- causal GQA attention, no-online-softmax --------------------
// RMSNorm bounds |score| <= sqrt(128) = 11.32, so exp(s) <= 8.2e4 and
// l <= 2048*8.2e4 = 1.7e8: direct exp2 accumulation is f32/bf16-safe.
// T14 async-STAGE with NAMED uint4 regs (rule #20: arrays kr[4]/vr[4] were
// demoted to scratch regardless of launch-bounds cap; named scalars fixed it
// -- round 4: attn dropped out of top-5, total 690->578).
__global__ __launch_bounds__(256, 2) void attn_kernel(
    const unsigned short* __restrict__ qb, const unsigned short* __restrict__ kb,
    const unsigned short* __restrict__ vt, unsigned short* __restrict__ aout) {
  __shared__ unsigned short smem[27136];      // 54272 B total
  unsigned short* Ks = smem;                  // [64][136]  272B rows
  unsigned short* Vs = smem + 8704;           // [128][72]  144B rows
  unsigned short* Ps = smem + 17920;          // [4][32][72] per-wave P
  const int bx = blockIdx.x;
  const int kvh = blockIdx.y;
  const int qt = (kvh < 4) ? bx : (63 - bx);  // complementary CU pairing
  const int q0 = qt * 32;
  const int tid = threadIdx.x, lane = tid & 63, wv = tid >> 6;
  const int h = kvh * 4 + wv;
  const int quad = lane >> 4, mc = lane & 15;
  const float c2 = 0.1275356394f;  // log2(e)/sqrt(128)
  const __bf16 one = (__bf16)1.0f;
  const bf16x8 ones = {one, one, one, one, one, one, one, one};
  bf16x8 qf[2][4];
#pragma unroll
  for (int mi = 0; mi < 2; mi++)
#pragma unroll
    for (int kc = 0; kc < 4; kc++)
      qf[mi][kc] = *(const bf16x8*)(
          qb + ((size_t)(q0 + mi * 16 + mc) * NQH + h) * HD + kc * 32 + quad * 8);

  const unsigned short* kbase = kb + ((size_t)(tid >> 4) * NKVH + kvh) * HD + (tid & 15) * 8;
  const unsigned short* vbase = vt + ((size_t)kvh * HD + (tid >> 3)) * T_SEQ + (tid & 7) * 8;
  unsigned short* kdst = Ks + (tid >> 4) * 136 + (tid & 15) * 8;
  unsigned short* vdst = Vs + (tid >> 3) * 72 + (tid & 7) * 8;
  const size_t kstep = (size_t)16 * (NKVH * HD);   // 16 K-rows
  const size_t vstep = (size_t)32 * T_SEQ;         // 32 V-d-rows

  floatx4 O[2][8] = {};
  floatx4 lac[2] = {};
  const int ntiles = (qt >> 1) + 1;

  // prologue: tile 0 global->reg (named regs, static uses only)
  uint4 kr0 = *(const uint4*)(kbase);
  uint4 kr1 = *(const uint4*)(kbase + kstep);
  uint4 kr2 = *(const uint4*)(kbase + 2 * kstep);
  uint4 kr3 = *(const uint4*)(kbase + 3 * kstep);
  uint4 vr0 = *(const uint4*)(vbase);
  uint4 vr1 = *(const uint4*)(vbase + vstep);
  uint4 vr2 = *(const uint4*)(vbase + 2 * vstep);
  uint4 vr3 = *(const uint4*)(vbase + 3 * vstep);

  for (int it = 0; it < ntiles; it++) {
    const int s0 = it * 64;
    __syncthreads();  // prev iter LDS readers done
    // reg -> LDS (waits on loads issued one compute-phase ago)
    *(uint4*)(kdst)                = kr0;
    *(uint4*)(kdst + 16 * 136)     = kr1;
    *(uint4*)(kdst + 32 * 136)     = kr2;
    *(uint4*)(kdst + 48 * 136)     = kr3;
    *(uint4*)(vdst)                = vr0;
    *(uint4*)(vdst + 32 * 72)      = vr1;
    *(uint4*)(vdst + 64 * 72)      = vr2;
    *(uint4*)(vdst + 96 * 72)      = vr3;
    // issue next tile's global loads NOW; they fly during this tile's compute
    if (it + 1 < ntiles) {
      const int s0n = s0 + 64;
      const unsigned short* kn = kbase + (size_t)s0n * (NKVH * HD);
      const unsigned short* vn = vbase + s0n;
      kr0 = *(const uint4*)(kn);
      kr1 = *(const uint4*)(kn + kstep);
      kr2 = *(const uint4*)(kn + 2 * kstep);
      kr3 = *(const uint4*)(kn + 3 * kstep);
      vr0 = *(const uint4*)(vn);
      vr1 = *(const uint4*)(vn + vstep);
      vr2 = *(const uint4*)(vn + 2 * vstep);
      vr3 = *(const uint4*)(vn + 3 * vstep);
    }
    __syncthreads();
    // S = Q K^T -> p = exp2(S*c2) masked -> Ps (A-layout round trip)
#pragma unroll
    for (int jt = 0; jt < 4; jt++) {
      bf16x8 bfr[4];
#pragma unroll
      for (int kc = 0; kc < 4; kc++)
        bfr[kc] = *(const bf16x8*)(Ks + (jt * 16 + mc) * 136 + kc * 32 + quad * 8);
#pragma unroll
      for (int mi = 0; mi < 2; mi++) {
        floatx4 acc = {};
        __builtin_amdgcn_s_setprio(1);
#pragma unroll
        for (int kc = 0; kc < 4; kc++)
          acc = __builtin_amdgcn_mfma_f32_16x16x32_bf16(qf[mi][kc], bfr[kc], acc, 0, 0, 0);
        __builtin_amdgcn_s_setprio(0);
        int qrow = q0 + mi * 16 + quad * 4;
        int scol = s0 + jt * 16 + mc;
#pragma unroll
        for (int r = 0; r < 4; r++) {
          float p = (scol <= qrow + r) ? exp2f(acc[r] * c2) : 0.f;
          Ps[(size_t)(wv * 32 + mi * 16 + quad * 4 + r) * 72 + jt * 16 + mc] = f2bf(p);
        }
      }
    }
    // P A-frags (in-wave DS ordering; Ps region is wave-private)
    bf16x8 pa[2][2];
#pragma unroll
    for (int mi = 0; mi < 2; mi++)
#pragma unroll
      for (int kb2 = 0; kb2 < 2; kb2++)
        pa[mi][kb2] = *(const bf16x8*)(Ps + (size_t)(wv * 32 + mi * 16 + mc) * 72 + kb2 * 32 + quad * 8);
    // row-sum l via MFMA with ones-B (no shuffles)
    __builtin_amdgcn_s_setprio(1);
#pragma unroll
    for (int mi = 0; mi < 2; mi++) {
      lac[mi] = __builtin_amdgcn_mfma_f32_16x16x32_bf16(pa[mi][0], ones, lac[mi], 0, 0, 0);
      lac[mi] = __builtin_amdgcn_mfma_f32_16x16x32_bf16(pa[mi][1], ones, lac[mi], 0, 0, 0);
    }
    __builtin_amdgcn_s_setprio(0);
    // O += P V
#pragma unroll
    for (int jd = 0; jd < 8; jd++) {
      bf16x8 vb0 = *(const bf16x8*)(Vs + (jd * 16 + mc) * 72 + quad * 8);
      bf16x8 vb1 = *(const bf16x8*)(Vs + (jd * 16 + mc) * 72 + 32 + quad * 8);
      __builtin_amdgcn_s_setprio(1);
#pragma unroll
      for (int mi = 0; mi < 2; mi++) {
        O[mi][jd] = __builtin_amdgcn_mfma_f32_16x16x32_bf16(pa[mi][0], vb0, O[mi][jd], 0, 0, 0);
        O[mi][jd] = __builtin_amdgcn_mfma_f32_16x16x32_bf16(pa[mi][1], vb1, O[mi][jd], 0, 0, 0);
      }
      __builtin_amdgcn_s_setprio(0);
    }
  }
  // coalesced epilogue: stage O/l via LDS (reuse whole smem), 16B stores
  __syncthreads();
  float rl[2][4];
#pragma unroll
  for (int mi = 0; mi < 2; mi++)
#pragma unroll
    for (int r = 0; r < 4; r++) rl[mi][r] = 1.0f / lac[mi][r];
#pragma unroll
  for (int mi = 0; mi < 2; mi++)
#pragma unroll
    for (int jd = 0; jd < 8; jd++)
#pragma unroll
      for (int r = 0; r < 4; r++)
        smem[(size_t)(wv * 32 + mi * 16 + quad * 4 + r) * 128 + jd * 16 + mc] =
            f2bf(O[mi][jd][r] * rl[mi][r]);
  __syncthreads();
  const int rr = tid >> 1;            // 0..127: wave wv' = rr>>5, q-row rr&31
  const int cb = (tid & 1) * 64;
  const size_t gbase = (size_t)(q0 + (rr & 31)) * (NQH * HD) + (kvh * 4 + (rr >> 5)) * HD + cb;
#pragma unroll
  for (int i = 0; i < 8; i++) {
    uint4 v = *(const uint4*)(smem + (size_t)rr * 128 + cb + i * 8);
    *(uint4*)(aout + gbase + i * 8) = v;
  }
}

extern "C" void kernel_launch(void* const* d_in, const int* in_sizes, int n_in,
                              void* d_out, int out_size, void* d_ws, size_t ws_size,
                              hipStream_t stream) {
  const float* hidden    = (const float*)d_in[1];  // f32 [2048][4096]
  const float* w_qkv     = (const float*)d_in[2];  // f32 [4096][6144]
  const float* q_norm    = (const float*)d_in[3];  // f32 [128]
  const float* k_norm    = (const float*)d_in[4];  // f32 [128]
  const float* w_o       = (const float*)d_in[5];  // f32 [4096][4096]
  float* out             = (float*)d_out;          // f32 [2048][4096]
  char* ws = (char*)d_ws;
  unsigned short* wqkv_t   = (unsigned short*)(ws);
  unsigned short* q_bf     = (unsigned short*)(ws);               // [2048][32][128]
  unsigned short* k_bf     = (unsigned short*)(ws + 16777216);    // [2048][8][128]
  unsigned short* v_t      = (unsigned short*)(ws + 20971520);    // [8][128][2048]
  unsigned short* attn     = (unsigned short*)(ws + 25165824);    // [2048][4096]
  unsigned short* qkv_bf   = (unsigned short*)(ws + 50331648);    // [2048][6144]
  unsigned short* wo_t     = (unsigned short*)(ws + 50331648);    // [4096][4096]
  unsigned short* hidden_b = (unsigned short*)(ws + 75497472);    // [2048][4096]

  cast_f32_bf16<<<dim3((T_SEQ * HID) / 1024), 256, 0, stream>>>(hidden, hidden_b);
  transpose_f32_bf16<<<dim3(QKV_N / 64, HID / 64), 256, 0, stream>>>(w_qkv, wqkv_t, HID, QKV_N);
  gemm_bt2<256><<<dim3(QKV_N / 256, T_SEQ / 256), 512, 0, stream>>>(
      hidden_b, wqkv_t, nullptr, qkv_bf, T_SEQ, QKV_N, HID);
  normrope_kernel<<<dim3(T_SEQ, NQH + 2 * NKVH), 64, 0, stream>>>(
      qkv_bf, q_norm, k_norm, q_bf, k_bf, v_t);
  transpose_f32_bf16<<<dim3(HID / 64, HID / 64), 256, 0, stream>>>(w_o, wo_t, HID, HID);
  attn_kernel<<<dim3(T_SEQ / 32, NKVH), 256, 0, stream>>>(q_bf, k_bf, v_t, attn);
  gemm_bt2<128><<<dim3(HID / 128, T_SEQ / 256), 512, 0, stream>>>(
      attn, wo_t, out, nullptr, T_SEQ, HID, HID);
}